// Round 1
// 903.182 us; speedup vs baseline: 1.0391x; 1.0391x over previous
//
#include <hip/hip_runtime.h>

#define N_NODES 100000
#define N_EDGES 3200000
#define DIM 512
#define MPAD 100096      // 782*128
#define MTILES 782
#define BN_EPS 1e-5f

// histogram privatization geometry
#define RBITS 14
#define NBINS 16384      // 64 KB LDS of float bins
#define NRANGE 8         // 8*16384 = 131072 >= MPAD
#define NBLK 64          // edge-slice blocks per range
#define EDGES_PER_BLK (N_EDGES / NBLK)   // 50000 (divisible by 4)

typedef _Float16 half8 __attribute__((ext_vector_type(8)));
typedef float floatx4 __attribute__((ext_vector_type(4)));

// ---------------- conversion kernels ----------------

__global__ __launch_bounds__(256) void convert_x_kernel(const float* __restrict__ x,
                                                        _Float16* __restrict__ out) {
    size_t idx = ((size_t)blockIdx.x * 256 + threadIdx.x) * 8;
    int row = (int)(idx >> 9);
    half8 h;
    if (row < N_NODES) {
        const float4* p = (const float4*)(x + idx);
        float4 a = p[0], b = p[1];
        h[0] = (_Float16)a.x; h[1] = (_Float16)a.y; h[2] = (_Float16)a.z; h[3] = (_Float16)a.w;
        h[4] = (_Float16)b.x; h[5] = (_Float16)b.y; h[6] = (_Float16)b.z; h[7] = (_Float16)b.w;
    } else {
        #pragma unroll
        for (int k = 0; k < 8; ++k) h[k] = (_Float16)0.0f;
    }
    *(half8*)(out + idx) = h;
}

__global__ __launch_bounds__(256) void convert_w_kernel(const float* __restrict__ in,
                                                        _Float16* __restrict__ out) {
    size_t idx = ((size_t)blockIdx.x * 256 + threadIdx.x) * 8;  // < 262144
    const float4* p = (const float4*)(in + idx);
    float4 a = p[0], b = p[1];
    half8 h;
    h[0] = (_Float16)a.x; h[1] = (_Float16)a.y; h[2] = (_Float16)a.z; h[3] = (_Float16)a.w;
    h[4] = (_Float16)b.x; h[5] = (_Float16)b.y; h[6] = (_Float16)b.z; h[7] = (_Float16)b.w;
    *(half8*)(out + idx) = h;
}

// ---------------- graph scale: privatized LDS histogram ----------------
// deg pass (IS_DEG): bin 1.0f over dst where src!=dst.
// s pass:            bin dinv[dst] over src where src!=dst.
// XCD-aware swizzle (512 = 8 XCDs * 64): each XCD owns 8 slices x 8 ranges,
// so its resident blocks touch 8*400KB = 3.2 MB of edge data -> fits the
// 4 MB per-XCD L2 (previously 64 distinct slices = 25.6 MB footprint/XCD).
// Partials are non-atomic; stage-2 reduces 64 partials per bin.

template <bool IS_DEG>
__global__ __launch_bounds__(256) void hist_stage1(const int* __restrict__ ei,
                                                   const float* __restrict__ dinv,
                                                   float* __restrict__ part) {
    __shared__ float bins[NBINS];  // 64 KB
    const int tid = threadIdx.x;
    const int wg = (blockIdx.x & 7) * (NRANGE * NBLK / 8) + (blockIdx.x >> 3);
    const int r = wg & (NRANGE - 1);
    const int b = wg >> 3;
    for (int i = tid; i < NBINS; i += 256) bins[i] = 0.f;
    __syncthreads();

    const int e0 = b * EDGES_PER_BLK;
    const int e1 = e0 + EDGES_PER_BLK;
    const int lo = r << RBITS;
    const int hi = lo + NBINS;
    for (int e = e0 + tid * 4; e < e1; e += 256 * 4) {
        int4 sv = *(const int4*)(ei + e);
        int4 dv = *(const int4*)(ei + N_EDGES + e);
        const int ss[4] = {sv.x, sv.y, sv.z, sv.w};
        const int dd[4] = {dv.x, dv.y, dv.z, dv.w};
        #pragma unroll
        for (int k = 0; k < 4; ++k) {
            const int s = ss[k], d = dd[k];
            if (s == d) continue;
            const int key = IS_DEG ? d : s;
            if (key >= lo && key < hi) {
                const float val = IS_DEG ? 1.0f : dinv[d];
                atomicAdd(&bins[key - lo], val);
            }
        }
    }
    __syncthreads();

    float* dst = part + (size_t)wg * NBINS;
    for (int i = tid; i < NBINS; i += 256) dst[i] = bins[i];
}

__global__ __launch_bounds__(256) void hist_stage2_deg(const float* __restrict__ part,
                                                       float* __restrict__ dinv,
                                                       float* __restrict__ sarr) {
    const int i = blockIdx.x * 256 + threadIdx.x;
    if (i >= MPAD) return;
    const int r = i >> RBITS, bin = i & (NBINS - 1);
    float h = 0.f;
    #pragma unroll 8
    for (int b = 0; b < NBLK; ++b)
        h += part[(size_t)(b * NRANGE + r) * NBINS + bin];
    if (i < N_NODES) {
        const float deg = h + 1.0f;    // +1 self-loop
        dinv[i] = rsqrtf(deg);
        sarr[i] = 1.0f / deg;          // self-loop term of s
    } else {
        dinv[i] = 0.f;
        sarr[i] = 0.f;
    }
}

__global__ __launch_bounds__(256) void hist_stage2_s(const float* __restrict__ part,
                                                     const float* __restrict__ dinv,
                                                     float* __restrict__ sarr) {
    const int i = blockIdx.x * 256 + threadIdx.x;
    if (i >= MPAD) return;
    const int r = i >> RBITS, bin = i & (NBINS - 1);
    float t = 0.f;
    #pragma unroll 8
    for (int b = 0; b < NBLK; ++b)
        t += part[(size_t)(b * NRANGE + r) * NBINS + bin];
    if (i < N_NODES) sarr[i] += dinv[i] * t;
}

// ---------------- GEMM: C[m,n] = (sum_k A[m,k]*W[n,k]) * s[m] + bias[n] ----------------
// 128x128 tile, BK=32, 4 waves in 2x2 (each 64x64 via 4x4 of 16x16x32 MFMA).
// Double-buffered LDS with single-barrier-per-tile prefetch (T3 minimum
// 2-phase): stage(next) is issued BEFORE compute(cur), so global->LDS latency
// overlaps ds_read+MFMA, and barrier count is halved vs the old structure.
// XCD-aware swizzle (3128 = 8 XCDs * 391): the 4 column-tile blocks sharing
// an A row-tile become consecutive on ONE XCD -> A fetched once per L2.
// !FINAL: store f16, accumulate column sum/sumsq (rows < N_NODES only).
// FINAL:  store f32 to d_out, rows < N_NODES only.

template <bool FINAL>
__global__ __launch_bounds__(256) void gemm_kernel(
    const _Float16* __restrict__ A,     // [MPAD][512]
    const _Float16* __restrict__ W,     // [512][512] (row = output channel)
    const float* __restrict__ sarr,     // [MPAD]
    const float* __restrict__ bias,     // [512]
    void* __restrict__ out,
    float* __restrict__ colsum,
    float* __restrict__ colsq)
{
    __shared__ _Float16 As[2][128 * 32];
    __shared__ _Float16 Bs[2][128 * 32];
    __shared__ float lsum[128];
    __shared__ float lsq[128];

    const int tid  = threadIdx.x;
    const int wave = tid >> 6;
    const int lane = tid & 63;
    const int quad = lane >> 4;
    const int l16  = lane & 15;

    // bijective XCD swizzle: grid 3128 = 8 * 391
    const int wg = (blockIdx.x & 7) * (MTILES * 4 / 8) + (blockIdx.x >> 3);
    const int ct = wg & 3;   // 4 column tiles (512/128)
    const int rt = wg >> 2;  // 782 row tiles
    const int m0 = rt * 128;
    const int n0 = ct * 128;
    const int wm = (wave >> 1) * 64;
    const int wn = (wave & 1) * 64;

    floatx4 acc[4][4];
    #pragma unroll
    for (int i = 0; i < 4; ++i)
        #pragma unroll
        for (int j = 0; j < 4; ++j)
            acc[i][j] = (floatx4){0.f, 0.f, 0.f, 0.f};

    const int f0 = wave * 1024 + lane * 16;  // 0..4080 (byte offset within half-tile)
    const int ra = f0 >> 6;                  // row within 64-row half
    const int ca = f0 & 63;                  // byte col within row

    const char* Ab = (const char*)(A + (size_t)m0 * DIM) + ca;
    const char* Bb = (const char*)(W + (size_t)n0 * DIM) + ca;

    auto stage = [&](int buf, int kb) {
        #pragma unroll
        for (int is = 0; is < 2; ++is) {
            const int r = is * 64 + ra;
            __builtin_amdgcn_global_load_lds(
                (const __attribute__((address_space(1))) void*)(Ab + (size_t)r * (DIM * 2) + kb * 2),
                (__attribute__((address_space(3))) void*)(&As[buf][is * 2048 + (f0 >> 1)]),
                16, 0, 0);
            __builtin_amdgcn_global_load_lds(
                (const __attribute__((address_space(1))) void*)(Bb + (size_t)r * (DIM * 2) + kb * 2),
                (__attribute__((address_space(3))) void*)(&Bs[buf][is * 2048 + (f0 >> 1)]),
                16, 0, 0);
        }
    };

    auto compute = [&](int buf) {
        half8 af[4], bfr[4];
        #pragma unroll
        for (int i = 0; i < 4; ++i)
            af[i] = *(const half8*)(&As[buf][(wm + i * 16 + l16) * 32 + quad * 8]);
        #pragma unroll
        for (int j = 0; j < 4; ++j)
            bfr[j] = *(const half8*)(&Bs[buf][(wn + j * 16 + l16) * 32 + quad * 8]);
        #pragma unroll
        for (int i = 0; i < 4; ++i)
            #pragma unroll
            for (int j = 0; j < 4; ++j)
                acc[i][j] = __builtin_amdgcn_mfma_f32_16x16x32_f16(af[i], bfr[j], acc[i][j], 0, 0, 0);
    };

    // prologue: tile 0 into buf0
    stage(0, 0);
    __syncthreads();

    // 16 K-tiles total; pairs of (stage-next, compute-cur, barrier)
    int kb = 32;
    for (int it = 0; it < 7; ++it) {
        stage(1, kb);          // prefetch tile into buf1 (overlaps compute below)
        compute(0);
        __syncthreads();       // drains vmcnt(0): buf1 ready, buf0 free
        stage(0, kb + 32);
        compute(1);
        __syncthreads();
        kb += 64;
    }
    stage(1, kb);              // kb == 480: last tile
    compute(0);
    __syncthreads();
    compute(1);

    // epilogue
    if (!FINAL) {
        if (tid < 128) { lsum[tid] = 0.f; lsq[tid] = 0.f; }
        __syncthreads();
    }

    float4 sva[4];
    #pragma unroll
    for (int i = 0; i < 4; ++i)
        sva[i] = *(const float4*)(sarr + m0 + wm + i * 16 + quad * 4);
    float bv[4];
    #pragma unroll
    for (int j = 0; j < 4; ++j)
        bv[j] = bias[n0 + wn + j * 16 + l16];

    #pragma unroll
    for (int j = 0; j < 4; ++j) {
        const int col_g = n0 + wn + j * 16 + l16;
        float cs = 0.f, cq = 0.f;
        #pragma unroll
        for (int i = 0; i < 4; ++i) {
            const int rbase = m0 + wm + i * 16 + quad * 4;
            #pragma unroll
            for (int r = 0; r < 4; ++r) {
                const int row_g = rbase + r;
                const float sval = ((const float*)&sva[i])[r];
                const float yv = acc[i][j][r] * sval + bv[j];
                if (FINAL) {
                    if (row_g < N_NODES)
                        ((float*)out)[(size_t)row_g * DIM + col_g] = yv;
                } else {
                    ((_Float16*)out)[(size_t)row_g * DIM + col_g] = (_Float16)yv;
                    if (row_g < N_NODES) { cs += yv; cq += yv * yv; }
                }
            }
        }
        if (!FINAL) {
            atomicAdd(&lsum[wn + j * 16 + l16], cs);
            atomicAdd(&lsq[wn + j * 16 + l16], cq);
        }
    }
    if (!FINAL) {
        __syncthreads();
        if (tid < 128) {
            atomicAdd(&colsum[n0 + tid], lsum[tid]);
            atomicAdd(&colsq[n0 + tid], lsq[tid]);
        }
    }
}

// ---------------- batchnorm ----------------

__global__ void bn_finalize(const float* __restrict__ colsum, const float* __restrict__ colsq,
                            float* __restrict__ mu, float* __restrict__ rstd) {
    int c = threadIdx.x;  // 512 threads
    float m = colsum[c] * (1.0f / (float)N_NODES);
    float v = colsq[c] * (1.0f / (float)N_NODES) - m * m;
    mu[c] = m;
    rstd[c] = rsqrtf(v + BN_EPS);
}

__global__ __launch_bounds__(256) void bn_apply(_Float16* __restrict__ y,
                                                const float* __restrict__ mu,
                                                const float* __restrict__ rstd) {
    size_t idx = ((size_t)blockIdx.x * 256 + threadIdx.x) * 8;
    int row = (int)(idx >> 9);
    int col = (int)(idx & 511);
    half8 h;
    if (row < N_NODES) {
        h = *(const half8*)(y + idx);
        float4 m0 = *(const float4*)(mu + col);
        float4 m1 = *(const float4*)(mu + col + 4);
        float4 r0 = *(const float4*)(rstd + col);
        float4 r1 = *(const float4*)(rstd + col + 4);
        float mus[8] = {m0.x, m0.y, m0.z, m0.w, m1.x, m1.y, m1.z, m1.w};
        float rs[8]  = {r0.x, r0.y, r0.z, r0.w, r1.x, r1.y, r1.z, r1.w};
        #pragma unroll
        for (int k = 0; k < 8; ++k) {
            float v = ((float)h[k] - mus[k]) * rs[k];
            h[k] = (_Float16)fmaxf(v, 0.f);
        }
    } else {
        #pragma unroll
        for (int k = 0; k < 8; ++k) h[k] = (_Float16)0.0f;  // zero pad rows
    }
    *(half8*)(y + idx) = h;
}

// ---------------- launch ----------------

extern "C" void kernel_launch(void* const* d_in, const int* in_sizes, int n_in,
                              void* d_out, int out_size, void* d_ws, size_t ws_size,
                              hipStream_t stream) {
    const float* graph_node = (const float*)d_in[0];
    const int*   edge_index = (const int*)d_in[1];
    const float* W0 = (const float*)d_in[2];
    const float* b0 = (const float*)d_in[3];
    const float* W1 = (const float*)d_in[4];
    const float* b1 = (const float*)d_in[5];
    const float* W2 = (const float*)d_in[6];
    const float* b2 = (const float*)d_in[7];

    char* ws = (char*)d_ws;
    const size_t XB = (size_t)MPAD * DIM * 2;           // one f16 activation buffer
    _Float16* x0  = (_Float16*)ws;                      // XB bytes
    _Float16* wf  = (_Float16*)(ws + XB);               // 3*512*512 f16
    float* dinv   = (float*)(ws + XB + 3 * DIM * DIM * 2);
    float* sarr   = dinv + MPAD;
    float* stats  = sarr + MPAD;                        // 4096 floats
    float *sum0 = stats,        *sq0 = stats + 512,  *mu0 = stats + 1024, *rstd0 = stats + 1536;
    float *sum1 = stats + 2048, *sq1 = stats + 2560, *mu1 = stats + 3072, *rstd1 = stats + 3584;

    // layer-0/1 intermediate lives in d_out (f16, 102.5 MB < 204.8 MB)
    _Float16* x1 = (_Float16*)d_out;
    // histogram partials live in the unused upper region of d_out during the
    // graph phase: 512 blocks x 64 KB = 32 MB at offset 110 MiB (output is
    // 204.8 MB; x1 occupies the first 102.5 MB and is written only later).
    float* part = (float*)((char*)d_out + (size_t)110 * 1024 * 1024);

    hipMemsetAsync(stats, 0, 4096 * sizeof(float), stream);

    const int elemBlocks = MPAD * DIM / 8 / 256;        // 25024
    convert_x_kernel<<<elemBlocks, 256, 0, stream>>>(graph_node, x0);
    convert_w_kernel<<<128, 256, 0, stream>>>(W0, wf);
    convert_w_kernel<<<128, 256, 0, stream>>>(W1, wf + 262144);
    convert_w_kernel<<<128, 256, 0, stream>>>(W2, wf + 524288);

    const int statBlocks = (MPAD + 255) / 256;          // 391
    hist_stage1<true><<<NRANGE * NBLK, 256, 0, stream>>>(edge_index, dinv, part);
    hist_stage2_deg<<<statBlocks, 256, 0, stream>>>(part, dinv, sarr);
    hist_stage1<false><<<NRANGE * NBLK, 256, 0, stream>>>(edge_index, dinv, part);
    hist_stage2_s<<<statBlocks, 256, 0, stream>>>(part, dinv, sarr);

    // layer 0: x0 -> x1 (d_out region)
    gemm_kernel<false><<<MTILES * 4, 256, 0, stream>>>(x0, wf, sarr, b0, x1, sum0, sq0);
    bn_finalize<<<1, 512, 0, stream>>>(sum0, sq0, mu0, rstd0);
    bn_apply<<<elemBlocks, 256, 0, stream>>>(x1, mu0, rstd0);

    // layer 1: x1 -> x0
    gemm_kernel<false><<<MTILES * 4, 256, 0, stream>>>(x1, wf + 262144, sarr, b1, x0, sum1, sq1);
    bn_finalize<<<1, 512, 0, stream>>>(sum1, sq1, mu1, rstd1);
    bn_apply<<<elemBlocks, 256, 0, stream>>>(x0, mu1, rstd1);

    // layer 2: x0 -> d_out (f32, masked rows < N)
    gemm_kernel<true><<<MTILES * 4, 256, 0, stream>>>(x0, wf + 524288, sarr, b2, d_out,
                                                      nullptr, nullptr);
}

// Round 2
// 857.058 us; speedup vs baseline: 1.0950x; 1.0538x over previous
//
#include <hip/hip_runtime.h>

#define N_NODES 100000
#define N_EDGES 3200000
#define DIM 512
#define MPAD 100096      // 391*256
#define BN_EPS 1e-5f

// GEMM geometry: 256x256 tile, BK=64, 8 waves, 8-phase counted-vmcnt schedule
#define GRTILES 391      // MPAD/256
#define GGRID 782        // GRTILES * 2 column tiles

// histogram privatization geometry
#define RBITS 14
#define NBINS 16384      // 64 KB LDS of float bins
#define NRANGE 8         // 8*16384 = 131072 >= MPAD
#define NBLK 64          // edge-slice blocks per range
#define EDGES_PER_BLK (N_EDGES / NBLK)   // 50000 (divisible by 4)

typedef _Float16 half8 __attribute__((ext_vector_type(8)));
typedef float floatx4 __attribute__((ext_vector_type(4)));

// ---------------- conversion kernels ----------------

__global__ __launch_bounds__(256) void convert_x_kernel(const float* __restrict__ x,
                                                        _Float16* __restrict__ out) {
    size_t idx = ((size_t)blockIdx.x * 256 + threadIdx.x) * 8;
    int row = (int)(idx >> 9);
    half8 h;
    if (row < N_NODES) {
        const float4* p = (const float4*)(x + idx);
        float4 a = p[0], b = p[1];
        h[0] = (_Float16)a.x; h[1] = (_Float16)a.y; h[2] = (_Float16)a.z; h[3] = (_Float16)a.w;
        h[4] = (_Float16)b.x; h[5] = (_Float16)b.y; h[6] = (_Float16)b.z; h[7] = (_Float16)b.w;
    } else {
        #pragma unroll
        for (int k = 0; k < 8; ++k) h[k] = (_Float16)0.0f;
    }
    *(half8*)(out + idx) = h;
}

__global__ __launch_bounds__(256) void convert_w_kernel(const float* __restrict__ in,
                                                        _Float16* __restrict__ out) {
    size_t idx = ((size_t)blockIdx.x * 256 + threadIdx.x) * 8;  // < 262144
    const float4* p = (const float4*)(in + idx);
    float4 a = p[0], b = p[1];
    half8 h;
    h[0] = (_Float16)a.x; h[1] = (_Float16)a.y; h[2] = (_Float16)a.z; h[3] = (_Float16)a.w;
    h[4] = (_Float16)b.x; h[5] = (_Float16)b.y; h[6] = (_Float16)b.z; h[7] = (_Float16)b.w;
    *(half8*)(out + idx) = h;
}

// ---------------- graph scale: privatized LDS histogram ----------------

template <bool IS_DEG>
__global__ __launch_bounds__(256) void hist_stage1(const int* __restrict__ ei,
                                                   const float* __restrict__ dinv,
                                                   float* __restrict__ part) {
    __shared__ float bins[NBINS];  // 64 KB
    const int tid = threadIdx.x;
    const int wg = (blockIdx.x & 7) * (NRANGE * NBLK / 8) + (blockIdx.x >> 3);
    const int r = wg & (NRANGE - 1);
    const int b = wg >> 3;
    for (int i = tid; i < NBINS; i += 256) bins[i] = 0.f;
    __syncthreads();

    const int e0 = b * EDGES_PER_BLK;
    const int e1 = e0 + EDGES_PER_BLK;
    const int lo = r << RBITS;
    const int hi = lo + NBINS;
    for (int e = e0 + tid * 4; e < e1; e += 256 * 4) {
        int4 sv = *(const int4*)(ei + e);
        int4 dv = *(const int4*)(ei + N_EDGES + e);
        const int ss[4] = {sv.x, sv.y, sv.z, sv.w};
        const int dd[4] = {dv.x, dv.y, dv.z, dv.w};
        #pragma unroll
        for (int k = 0; k < 4; ++k) {
            const int s = ss[k], d = dd[k];
            if (s == d) continue;
            const int key = IS_DEG ? d : s;
            if (key >= lo && key < hi) {
                const float val = IS_DEG ? 1.0f : dinv[d];
                atomicAdd(&bins[key - lo], val);
            }
        }
    }
    __syncthreads();

    float* dst = part + (size_t)wg * NBINS;
    for (int i = tid; i < NBINS; i += 256) dst[i] = bins[i];
}

__global__ __launch_bounds__(256) void hist_stage2_deg(const float* __restrict__ part,
                                                       float* __restrict__ dinv,
                                                       float* __restrict__ sarr) {
    const int i = blockIdx.x * 256 + threadIdx.x;
    if (i >= MPAD) return;
    const int r = i >> RBITS, bin = i & (NBINS - 1);
    float h = 0.f;
    #pragma unroll 8
    for (int b = 0; b < NBLK; ++b)
        h += part[(size_t)(b * NRANGE + r) * NBINS + bin];
    if (i < N_NODES) {
        const float deg = h + 1.0f;    // +1 self-loop
        dinv[i] = rsqrtf(deg);
        sarr[i] = 1.0f / deg;          // self-loop term of s
    } else {
        dinv[i] = 0.f;
        sarr[i] = 0.f;
    }
}

__global__ __launch_bounds__(256) void hist_stage2_s(const float* __restrict__ part,
                                                     const float* __restrict__ dinv,
                                                     float* __restrict__ sarr) {
    const int i = blockIdx.x * 256 + threadIdx.x;
    if (i >= MPAD) return;
    const int r = i >> RBITS, bin = i & (NBINS - 1);
    float t = 0.f;
    #pragma unroll 8
    for (int b = 0; b < NBLK; ++b)
        t += part[(size_t)(b * NRANGE + r) * NBINS + bin];
    if (i < N_NODES) sarr[i] += dinv[i] * t;
}

// ---------------- GEMM: C[m,n] = (sum_k A[m,k]*W[n,k]) * s[m] + bias[n] ----------------
// 256x256 tile, BK=64, 8 waves (2M x 4N), 8-phase schedule with counted vmcnt.
// LDS 128 KB: smem[buf][A/B][half][128x64 f16], subtiled [16rows x 32cols]
// (1 KB subtiles) with XOR-bit5<-bit9 bank swizzle. global_load_lds writes
// LINEARLY; the swizzle is realized by inverse-permuting the per-lane GLOBAL
// source address (rule: both-sides-or-neither). Even K-tiles -> buf0, odd ->
// buf1. Stage slots: ph1-3 refill buf1 (A1,B0,B1 of kt 2t+1), ph4-7 refill
// buf0 (kt 2t+2, A first: HBM latency gets 3-4 phases of cover; B is
// L2-resident W), ph8 stages A0 of kt 2t+3. vmcnt(2) only at ph4/ph8.

#define BARRIER __builtin_amdgcn_s_barrier()
#define WAIT_LGKM do { asm volatile("s_waitcnt lgkmcnt(0)" ::: "memory"); \
                       __builtin_amdgcn_sched_barrier(0); } while (0)
#define VM2 do { asm volatile("s_waitcnt vmcnt(2)" ::: "memory"); \
                 __builtin_amdgcn_sched_barrier(0); } while (0)
#define VM0 do { asm volatile("s_waitcnt vmcnt(0)" ::: "memory"); \
                 __builtin_amdgcn_sched_barrier(0); } while (0)
#define VM8 do { asm volatile("s_waitcnt vmcnt(8)" ::: "memory"); \
                 __builtin_amdgcn_sched_barrier(0); } while (0)
#define VNONE ((void)0)
#define PRIO1 __builtin_amdgcn_s_setprio(1)
#define PRIO0 __builtin_amdgcn_s_setprio(0)

#define STG(buf, ab, h, kt) do { \
    const char* _s = (ab) ? Bsrc : Asrc; \
    __builtin_amdgcn_global_load_lds( \
        (const __attribute__((address_space(1))) void*)(_s + (size_t)((h)*128 + rowS0)*1024 + (kt)*128 + cbS), \
        (__attribute__((address_space(3))) void*)(&smem[buf][ab][h][tid*8]), 16, 0, 0); \
    __builtin_amdgcn_global_load_lds( \
        (const __attribute__((address_space(1))) void*)(_s + (size_t)((h)*128 + rowS0 + 64)*1024 + (kt)*128 + cbS), \
        (__attribute__((address_space(3))) void*)(&smem[buf][ab][h][4096 + tid*8]), 16, 0, 0); \
} while (0)

#define RDA(base, i0) do { \
    _Pragma("unroll") for (int ii = 0; ii < 4; ++ii) \
        _Pragma("unroll") for (int s = 0; s < 2; ++s) \
            fa[ii][s] = *(const half8*)((const char*)(base) + ((i0) + ii) * 2048 + s * 1024 + inb); \
} while (0)

#define RDB(base, j0) do { \
    _Pragma("unroll") for (int jj = 0; jj < 2; ++jj) \
        _Pragma("unroll") for (int s = 0; s < 2; ++s) \
            fb[(j0) + jj][s] = *(const half8*)((const char*)(base) + (brow0 + (j0) + jj) * 2048 + s * 1024 + inb); \
} while (0)

#define MM(i0, j0) do { \
    _Pragma("unroll") for (int s = 0; s < 2; ++s) \
        _Pragma("unroll") for (int ii = 0; ii < 4; ++ii) \
            _Pragma("unroll") for (int jj = 0; jj < 2; ++jj) \
                acc[(i0)+ii][(j0)+jj] = __builtin_amdgcn_mfma_f32_16x16x32_f16( \
                    fa[ii][s], fb[(j0)+jj][s], acc[(i0)+ii][(j0)+jj], 0, 0, 0); \
} while (0)

// one iteration = 2 K-tiles (kt0 even from buf0, kt1 odd from buf1)
#define ITER(S13, S47, S8, KTA, KTB, KTC, VMP4, VMP8) do { \
    /* ph1 */ RDA(Ab0, 0); RDB(Bb0, 0); if (S13) STG(1, 0, 1, KTA); \
              BARRIER; WAIT_LGKM; PRIO1; MM(0, 0); PRIO0; BARRIER; \
    /* ph2 */ RDB(Bb0, 2); if (S13) STG(1, 1, 0, KTA); \
              BARRIER; WAIT_LGKM; PRIO1; MM(0, 2); PRIO0; BARRIER; \
    /* ph3 */ RDA(Ab0, 4); if (S13) STG(1, 1, 1, KTA); \
              BARRIER; WAIT_LGKM; PRIO1; MM(4, 0); PRIO0; BARRIER; \
    /* ph4 */ if (S47) STG(0, 0, 0, KTB); \
              BARRIER; PRIO1; MM(4, 2); PRIO0; VMP4; BARRIER; \
    /* ph5 */ RDA(Ab1, 0); RDB(Bb1, 0); if (S47) STG(0, 0, 1, KTB); \
              BARRIER; WAIT_LGKM; PRIO1; MM(0, 0); PRIO0; BARRIER; \
    /* ph6 */ RDB(Bb1, 2); if (S47) STG(0, 1, 0, KTB); \
              BARRIER; WAIT_LGKM; PRIO1; MM(0, 2); PRIO0; BARRIER; \
    /* ph7 */ RDA(Ab1, 4); if (S47) STG(0, 1, 1, KTB); \
              BARRIER; WAIT_LGKM; PRIO1; MM(4, 0); PRIO0; BARRIER; \
    /* ph8 */ if (S8) STG(1, 0, 0, KTC); \
              BARRIER; PRIO1; MM(4, 2); PRIO0; VMP8; BARRIER; \
} while (0)

template <bool FINAL>
__global__ __launch_bounds__(512, 2) void gemm_kernel(
    const _Float16* __restrict__ A,     // [MPAD][512]
    const _Float16* __restrict__ W,     // [512][512] (row = output channel)
    const float* __restrict__ sarr,     // [MPAD]
    const float* __restrict__ bias,     // [512]
    void* __restrict__ out,
    float* __restrict__ colsum,
    float* __restrict__ colsq)
{
    __shared__ _Float16 smem[2][2][2][8192];   // 128 KB exactly

    const int tid  = threadIdx.x;
    const int wave = tid >> 6;
    const int lane = tid & 63;
    const int quad = lane >> 4;
    const int l16  = lane & 15;

    // bijective XCD swizzle for grid 782 = 8*97 + 6 (m204 variant)
    const int xcd = blockIdx.x & 7, bidx = blockIdx.x >> 3;
    const int qq = 97, rr = 6;
    const int wg = (xcd < rr ? xcd * (qq + 1) : rr * (qq + 1) + (xcd - rr) * qq) + bidx;
    const int ct = wg & 1, rt = wg >> 1;
    const int m0 = rt * 256, n0 = ct * 256;

    const int wmh   = wave >> 2;         // A half this wave reads (C rows m0+wmh*128..)
    const int wnq   = wave & 3;          // C cols n0 + wnq*64
    const int bhalf = (wave >> 1) & 1;   // B half this wave reads
    const int brow0 = (wave & 1) * 4;    // local 16-row subtile base within B half

    const _Float16* Ab0 = &smem[0][0][wmh][0];
    const _Float16* Ab1 = &smem[1][0][wmh][0];
    const _Float16* Bb0 = &smem[0][1][bhalf][0];
    const _Float16* Bb1 = &smem[1][1][bhalf][0];

    // swizzled ds_read byte offset within a 1KB subtile
    const int inb = (l16 * 64 + quad * 16) ^ (((l16 >> 3) & 1) << 5);

    // stage source mapping: LDS linear dest byte D -> (row, colbyte) of the
    // subtiled+swizzled layout (XOR is an involution; bit9 unaffected by bit5)
    const int st0 = tid >> 6;
    int bsw = (tid & 63) * 16;
    bsw ^= ((bsw >> 9) & 1) << 5;
    const int rowS0 = ((st0 >> 1) << 4) + (bsw >> 6);
    const int cbS   = ((st0 & 1) << 6) + (bsw & 63);

    const char* Asrc = (const char*)(A + (size_t)m0 * DIM);
    const char* Bsrc = (const char*)(W + (size_t)n0 * DIM);

    floatx4 acc[8][4];
    #pragma unroll
    for (int i = 0; i < 8; ++i)
        #pragma unroll
        for (int j = 0; j < 4; ++j)
            acc[i][j] = (floatx4){0.f, 0.f, 0.f, 0.f};

    half8 fa[4][2];
    half8 fb[4][2];

    // prologue: kt0 -> buf0, kt1 -> buf1 (16 loads/thread)
    STG(0, 0, 0, 0); STG(0, 0, 1, 0); STG(0, 1, 0, 0); STG(0, 1, 1, 0);
    STG(1, 0, 0, 1); STG(1, 0, 1, 1); STG(1, 1, 0, 1); STG(1, 1, 1, 1);
    VM8;        // kt0's 8 loads complete; kt1's may remain in flight
    BARRIER;

    ITER(false, true,  true,  1, 2, 3, VM2, VM2);   // t=0 (kt1 came from prologue)
    ITER(true,  true,  true,  3, 4, 5, VM2, VM2);   // t=1
    ITER(true,  true,  true,  5, 6, 7, VM2, VM2);   // t=2
    ITER(true,  false, false, 7, 0, 0, VM0, VNONE); // t=3: tail (stages kt7 A1,B0,B1)

    // ---------------- epilogue ----------------
    float* lsum = (float*)&smem[0][0][0][0];
    float* lsq  = lsum + 256;
    if (!FINAL) {
        if (tid < 256) { lsum[tid] = 0.f; lsq[tid] = 0.f; }
        __syncthreads();
    }

    const int crow0 = m0 + wmh * 128;
    const int ccol0 = n0 + wnq * 64;
    #pragma unroll
    for (int j = 0; j < 4; ++j) {
        const int col_g = ccol0 + j * 16 + l16;
        const float bv = bias[col_g];
        float cs = 0.f, cq = 0.f;
        #pragma unroll
        for (int i = 0; i < 8; ++i) {
            const int rbase = crow0 + i * 16 + quad * 4;
            const float4 sv = *(const float4*)(sarr + rbase);
            #pragma unroll
            for (int r2 = 0; r2 < 4; ++r2) {
                const int row_g = rbase + r2;
                const float yv = acc[i][j][r2] * ((const float*)&sv)[r2] + bv;
                if (FINAL) {
                    if (row_g < N_NODES)
                        ((float*)out)[(size_t)row_g * DIM + col_g] = yv;
                } else {
                    ((_Float16*)out)[(size_t)row_g * DIM + col_g] = (_Float16)yv;
                    if (row_g < N_NODES) { cs += yv; cq += yv * yv; }
                }
            }
        }
        if (!FINAL) {
            atomicAdd(&lsum[wnq * 64 + j * 16 + l16], cs);
            atomicAdd(&lsq[wnq * 64 + j * 16 + l16], cq);
        }
    }
    if (!FINAL) {
        __syncthreads();
        if (tid < 256) {
            atomicAdd(&colsum[n0 + tid], lsum[tid]);
            atomicAdd(&colsq[n0 + tid], lsq[tid]);
        }
    }
}

// ---------------- batchnorm ----------------

__global__ void bn_finalize(const float* __restrict__ colsum, const float* __restrict__ colsq,
                            float* __restrict__ mu, float* __restrict__ rstd) {
    int c = threadIdx.x;  // 512 threads
    float m = colsum[c] * (1.0f / (float)N_NODES);
    float v = colsq[c] * (1.0f / (float)N_NODES) - m * m;
    mu[c] = m;
    rstd[c] = rsqrtf(v + BN_EPS);
}

__global__ __launch_bounds__(256) void bn_apply(_Float16* __restrict__ y,
                                                const float* __restrict__ mu,
                                                const float* __restrict__ rstd) {
    size_t idx = ((size_t)blockIdx.x * 256 + threadIdx.x) * 8;
    int row = (int)(idx >> 9);
    int col = (int)(idx & 511);
    half8 h;
    if (row < N_NODES) {
        h = *(const half8*)(y + idx);
        float4 m0 = *(const float4*)(mu + col);
        float4 m1 = *(const float4*)(mu + col + 4);
        float4 r0 = *(const float4*)(rstd + col);
        float4 r1 = *(const float4*)(rstd + col + 4);
        float mus[8] = {m0.x, m0.y, m0.z, m0.w, m1.x, m1.y, m1.z, m1.w};
        float rs[8]  = {r0.x, r0.y, r0.z, r0.w, r1.x, r1.y, r1.z, r1.w};
        #pragma unroll
        for (int k = 0; k < 8; ++k) {
            float v = ((float)h[k] - mus[k]) * rs[k];
            h[k] = (_Float16)fmaxf(v, 0.f);
        }
    } else {
        #pragma unroll
        for (int k = 0; k < 8; ++k) h[k] = (_Float16)0.0f;  // zero pad rows
    }
    *(half8*)(y + idx) = h;
}

// ---------------- launch ----------------

extern "C" void kernel_launch(void* const* d_in, const int* in_sizes, int n_in,
                              void* d_out, int out_size, void* d_ws, size_t ws_size,
                              hipStream_t stream) {
    const float* graph_node = (const float*)d_in[0];
    const int*   edge_index = (const int*)d_in[1];
    const float* W0 = (const float*)d_in[2];
    const float* b0 = (const float*)d_in[3];
    const float* W1 = (const float*)d_in[4];
    const float* b1 = (const float*)d_in[5];
    const float* W2 = (const float*)d_in[6];
    const float* b2 = (const float*)d_in[7];

    char* ws = (char*)d_ws;
    const size_t XB = (size_t)MPAD * DIM * 2;           // one f16 activation buffer
    _Float16* x0  = (_Float16*)ws;                      // XB bytes
    _Float16* wf  = (_Float16*)(ws + XB);               // 3*512*512 f16
    float* dinv   = (float*)(ws + XB + 3 * DIM * DIM * 2);
    float* sarr   = dinv + MPAD;
    float* stats  = sarr + MPAD;                        // 4096 floats
    float *sum0 = stats,        *sq0 = stats + 512,  *mu0 = stats + 1024, *rstd0 = stats + 1536;
    float *sum1 = stats + 2048, *sq1 = stats + 2560, *mu1 = stats + 3072, *rstd1 = stats + 3584;

    // layer-0/1 intermediate lives in d_out (f16, 102.5 MB < 204.8 MB)
    _Float16* x1 = (_Float16*)d_out;
    float* part = (float*)((char*)d_out + (size_t)110 * 1024 * 1024);

    hipMemsetAsync(stats, 0, 4096 * sizeof(float), stream);

    const int elemBlocks = MPAD * DIM / 8 / 256;        // 25024
    convert_x_kernel<<<elemBlocks, 256, 0, stream>>>(graph_node, x0);
    convert_w_kernel<<<128, 256, 0, stream>>>(W0, wf);
    convert_w_kernel<<<128, 256, 0, stream>>>(W1, wf + 262144);
    convert_w_kernel<<<128, 256, 0, stream>>>(W2, wf + 524288);

    const int statBlocks = (MPAD + 255) / 256;          // 391
    hist_stage1<true><<<NRANGE * NBLK, 256, 0, stream>>>(edge_index, dinv, part);
    hist_stage2_deg<<<statBlocks, 256, 0, stream>>>(part, dinv, sarr);
    hist_stage1<false><<<NRANGE * NBLK, 256, 0, stream>>>(edge_index, dinv, part);
    hist_stage2_s<<<statBlocks, 256, 0, stream>>>(part, dinv, sarr);

    // layer 0: x0 -> x1 (d_out region)
    gemm_kernel<false><<<GGRID, 512, 0, stream>>>(x0, wf, sarr, b0, x1, sum0, sq0);
    bn_finalize<<<1, 512, 0, stream>>>(sum0, sq0, mu0, rstd0);
    bn_apply<<<elemBlocks, 256, 0, stream>>>(x1, mu0, rstd0);

    // layer 1: x1 -> x0
    gemm_kernel<false><<<GGRID, 512, 0, stream>>>(x1, wf + 262144, sarr, b1, x0, sum1, sq1);
    bn_finalize<<<1, 512, 0, stream>>>(sum1, sq1, mu1, rstd1);
    bn_apply<<<elemBlocks, 256, 0, stream>>>(x0, mu1, rstd1);

    // layer 2: x0 -> d_out (f32, masked rows < N)
    gemm_kernel<true><<<GGRID, 512, 0, stream>>>(x0, wf + 524288, sarr, b2, d_out,
                                                 nullptr, nullptr);
}